// Round 9
// baseline (644.359 us; speedup 1.0000x reference)
//
#include <hip/hip_runtime.h>
#include <hip/hip_bf16.h>
#include <hip/hip_cooperative_groups.h>
#include <math.h>

#define NEG_SLOPE 0.2f

namespace cg = cooperative_groups;

typedef __attribute__((ext_vector_type(8))) short bf16x8;
typedef __attribute__((ext_vector_type(4))) float f32x4;

__device__ __forceinline__ float lrelu(float x) { return x > 0.f ? x : NEG_SLOPE * x; }
__device__ __forceinline__ float blo(unsigned u) { return __uint_as_float(u << 16); }
__device__ __forceinline__ float bhi(unsigned u) { return __uint_as_float(u & 0xffff0000u); }
__device__ __forceinline__ unsigned short f2b(float f) {
    __hip_bfloat16 b = __float2bfloat16(f);
    return *(unsigned short*)&b;
}

// ================= cooperative fused front end =================
// P0 zero deg + converts | P1 deg histogram | P2 two-level scan | P3 scatter + GEMM1 tiles.
// GEMM1: 128x128 tile, BK=32, LDS rows padded ->40 (2-way free), fused att1 dots.
__global__ __launch_bounds__(256, 2) void fused_front_kernel(
    const float* __restrict__ x, unsigned short* __restrict__ xb, long total8,
    const float* __restrict__ W1, unsigned short* __restrict__ W1T,
    const float* __restrict__ W2, unsigned short* __restrict__ W2T,
    const int* __restrict__ ei, int E, int EL,
    int* __restrict__ deg, int* __restrict__ bsum, int* __restrict__ bsoff,
    int* __restrict__ rowptr, int* __restrict__ cursor, int* __restrict__ csr_src,
    const float* __restrict__ att_src, const float* __restrict__ att_dst,
    unsigned short* __restrict__ xl1b, float* __restrict__ a_src, float* __restrict__ a_dst,
    int M, int n_tiles_y)
{
    cg::grid_group grid = cg::this_grid();
    __shared__ unsigned short As[128 * 40];
    __shared__ unsigned short Bs[128 * 40];
    __shared__ int red[256];
    __shared__ int part[256];

    const int tid   = threadIdx.x;
    const int gsize = gridDim.x * 256;
    const int gtid  = blockIdx.x * 256 + tid;

    for (int i = gtid; i < M; i += gsize) deg[i] = 0;
    for (long i = gtid; i < total8; i += gsize) {
        const float4* src = (const float4*)x + 2 * i;
        float4 a = src[0], v = src[1];
        uint4 pk;
        pk.x = (unsigned)f2b(a.x) | ((unsigned)f2b(a.y) << 16);
        pk.y = (unsigned)f2b(a.z) | ((unsigned)f2b(a.w) << 16);
        pk.z = (unsigned)f2b(v.x) | ((unsigned)f2b(v.y) << 16);
        pk.w = (unsigned)f2b(v.z) | ((unsigned)f2b(v.w) << 16);
        ((uint4*)xb)[i] = pk;
    }
    for (int i = gtid; i < 512 * 256; i += gsize) {
        int nn = i >> 8, k = i & 255;
        W1T[nn * 256 + k] = f2b(W1[k * 512 + nn]);
    }
    for (int i = gtid; i < 32 * 512; i += gsize) {
        int c = i >> 9, k = i & 511;
        W2T[c * 512 + k] = f2b(W2[k * 32 + c]);
    }
    grid.sync();

    for (int e = gtid; e < EL; e += gsize) {
        int d = (e < E) ? ei[E + e] : e - E;
        atomicAdd(&deg[d], 1);
    }
    grid.sync();

    const int nb = (M + 255) / 256;
    for (int b = blockIdx.x; b < nb; b += gridDim.x) {
        int i = b * 256 + tid;
        red[tid] = (i < M) ? deg[i] : 0;
        __syncthreads();
        for (int off = 128; off > 0; off >>= 1) {
            if (tid < off) red[tid] += red[tid + off];
            __syncthreads();
        }
        if (tid == 0) bsum[b] = red[0];
        __syncthreads();
    }
    grid.sync();

    if (blockIdx.x == 0) {
        int v = (tid < nb) ? bsum[tid] : 0;
        part[tid] = v;
        __syncthreads();
        for (int off = 1; off < 256; off <<= 1) {
            int tmp = (tid >= off) ? part[tid - off] : 0;
            __syncthreads();
            part[tid] += tmp;
            __syncthreads();
        }
        if (tid < nb) bsoff[tid] = part[tid] - v;
    }
    grid.sync();

    for (int b = blockIdx.x; b < nb; b += gridDim.x) {
        int i = b * 256 + tid;
        int v = (i < M) ? deg[i] : 0;
        part[tid] = v;
        __syncthreads();
        for (int off = 1; off < 256; off <<= 1) {
            int tmp = (tid >= off) ? part[tid - off] : 0;
            __syncthreads();
            part[tid] += tmp;
            __syncthreads();
        }
        if (i < M) {
            int r = bsoff[b] + part[tid] - v;
            rowptr[i] = r;
            cursor[i] = r;
        }
        if (i == M - 1) rowptr[M] = EL;
        __syncthreads();
    }
    grid.sync();

    for (int e = gtid; e < EL; e += gsize) {
        int s, d;
        if (e < E) { s = ei[e]; d = ei[E + e]; } else { s = d = e - E; }
        int pos = atomicAdd(&cursor[d], 1);
        csr_src[pos] = s;
    }

    const int wave = tid >> 6;
    const int wrow = wave >> 1;
    const int wcol = wave & 1;
    const int lane = tid & 63;
    const int quad = lane >> 4;
    const int l15  = lane & 15;
    const int sm = tid >> 1;
    const int sk = (tid & 1) * 16;

    const int n_tiles = 4 * n_tiles_y;
    for (int t = blockIdx.x; t < n_tiles; t += gridDim.x) {
        const int row0 = (t >> 2) * 128;
        const int col0 = (t & 3) * 128;
        f32x4 acc[4][4] = {};
        __syncthreads();
        for (int kb = 0; kb < 256; kb += 32) {
            uint4 a0 = make_uint4(0, 0, 0, 0), a1 = make_uint4(0, 0, 0, 0);
            if (row0 + sm < M) {
                const uint4* ap = (const uint4*)(xb + (size_t)(row0 + sm) * 256 + kb + sk);
                a0 = ap[0]; a1 = ap[1];
            }
            uint4* adp = (uint4*)&As[sm * 40 + sk];
            adp[0] = a0; adp[1] = a1;
            const uint4* bp = (const uint4*)(W1T + (size_t)(col0 + sm) * 256 + kb + sk);
            uint4* bd = (uint4*)&Bs[sm * 40 + sk];
            bd[0] = bp[0]; bd[1] = bp[1];
            __syncthreads();
            bf16x8 af[4], bf[4];
            #pragma unroll
            for (int mf = 0; mf < 4; ++mf)
                af[mf] = *(const bf16x8*)&As[(wrow * 64 + mf * 16 + l15) * 40 + quad * 8];
            #pragma unroll
            for (int nf = 0; nf < 4; ++nf)
                bf[nf] = *(const bf16x8*)&Bs[(wcol * 64 + nf * 16 + l15) * 40 + quad * 8];
            #pragma unroll
            for (int mf = 0; mf < 4; ++mf)
                #pragma unroll
                for (int nf = 0; nf < 4; ++nf)
                    acc[mf][nf] = __builtin_amdgcn_mfma_f32_16x16x32_bf16(
                        af[mf], bf[nf], acc[mf][nf], 0, 0, 0);
            __syncthreads();
        }
        const int h = (t & 3) * 2 + wcol;
        float asv[4], adv[4];
        #pragma unroll
        for (int nf = 0; nf < 4; ++nf) {
            asv[nf] = att_src[h * 64 + nf * 16 + l15];
            adv[nf] = att_dst[h * 64 + nf * 16 + l15];
        }
        #pragma unroll
        for (int mf = 0; mf < 4; ++mf) {
            #pragma unroll
            for (int r = 0; r < 4; ++r) {
                const int row = row0 + wrow * 64 + mf * 16 + quad * 4 + r;
                float sv = 0.f, tv = 0.f;
                #pragma unroll
                for (int nf = 0; nf < 4; ++nf) {
                    float v = acc[mf][nf][r];
                    sv += v * asv[nf];
                    tv += v * adv[nf];
                }
                sv += __shfl_xor(sv, 1); tv += __shfl_xor(tv, 1);
                sv += __shfl_xor(sv, 2); tv += __shfl_xor(tv, 2);
                sv += __shfl_xor(sv, 4); tv += __shfl_xor(tv, 4);
                sv += __shfl_xor(sv, 8); tv += __shfl_xor(tv, 8);
                if (row < M) {
                    #pragma unroll
                    for (int nf = 0; nf < 4; ++nf)
                        xl1b[(size_t)row * 512 + col0 + wcol * 64 + nf * 16 + l15] =
                            f2b(acc[mf][nf][r]);
                    if (l15 == 0) { a_src[row * 8 + h] = sv; a_dst[row * 8 + h] = tv; }
                }
            }
        }
    }
}

// ================= fallback front-end kernels (R6-proven) =================
__global__ __launch_bounds__(256) void prep_kernel(
    const float* __restrict__ x, unsigned short* __restrict__ xb, long total8,
    const float* __restrict__ W1, unsigned short* __restrict__ W1T,
    const float* __restrict__ W2, unsigned short* __restrict__ W2T,
    const int* __restrict__ ei, int E, int EL, int* __restrict__ deg,
    int b_cx, int b_cw)
{
    const int b = blockIdx.x;
    if (b < b_cx) {
        long i = (long)b * 256 + threadIdx.x;
        if (i >= total8) return;
        const float4* src = (const float4*)x + 2 * i;
        float4 a = src[0], v = src[1];
        uint4 pk;
        pk.x = (unsigned)f2b(a.x) | ((unsigned)f2b(a.y) << 16);
        pk.y = (unsigned)f2b(a.z) | ((unsigned)f2b(a.w) << 16);
        pk.z = (unsigned)f2b(v.x) | ((unsigned)f2b(v.y) << 16);
        pk.w = (unsigned)f2b(v.z) | ((unsigned)f2b(v.w) << 16);
        ((uint4*)xb)[i] = pk;
    } else if (b < b_cx + b_cw) {
        int i = (b - b_cx) * 256 + threadIdx.x;
        if (i < 512 * 256) {
            int nn = i >> 8, k = i & 255;
            W1T[nn * 256 + k] = f2b(W1[k * 512 + nn]);
        } else if (i < 512 * 256 + 32 * 512) {
            int j = i - 512 * 256;
            int c = j >> 9, k = j & 511;
            W2T[c * 512 + k] = f2b(W2[k * 32 + c]);
        }
    } else {
        int e = (b - b_cx - b_cw) * 256 + threadIdx.x;
        if (e >= EL) return;
        int d = (e < E) ? ei[E + e] : e - E;
        atomicAdd(&deg[d], 1);
    }
}

__global__ __launch_bounds__(256) void scan1_kernel(
    const int* __restrict__ deg, int* __restrict__ bsum, int n)
{
    __shared__ int red[256];
    int t = threadIdx.x, i = blockIdx.x * 256 + t;
    red[t] = (i < n) ? deg[i] : 0;
    __syncthreads();
    for (int off = 128; off > 0; off >>= 1) {
        if (t < off) red[t] += red[t + off];
        __syncthreads();
    }
    if (t == 0) bsum[blockIdx.x] = red[0];
}

__global__ __launch_bounds__(256) void scan2_kernel(
    const int* __restrict__ bsum, int* __restrict__ bsoff, int B)
{
    __shared__ int part[256];
    int t = threadIdx.x;
    int v = (t < B) ? bsum[t] : 0;
    part[t] = v;
    __syncthreads();
    for (int off = 1; off < 256; off <<= 1) {
        int tmp = (t >= off) ? part[t - off] : 0;
        __syncthreads();
        part[t] += tmp;
        __syncthreads();
    }
    if (t < B) bsoff[t] = part[t] - v;
}

__global__ __launch_bounds__(256) void scan3_kernel(
    const int* __restrict__ deg, const int* __restrict__ bsoff,
    int* __restrict__ rowptr, int* __restrict__ cursor, int n, int EL)
{
    __shared__ int part[256];
    int t = threadIdx.x, b = blockIdx.x, i = b * 256 + t;
    int v = (i < n) ? deg[i] : 0;
    part[t] = v;
    __syncthreads();
    for (int off = 1; off < 256; off <<= 1) {
        int tmp = (t >= off) ? part[t - off] : 0;
        __syncthreads();
        part[t] += tmp;
        __syncthreads();
    }
    if (i < n) {
        int r = bsoff[b] + part[t] - v;
        rowptr[i] = r;
        cursor[i] = r;
    }
    if (i == n - 1) rowptr[n] = EL;
}

__global__ __launch_bounds__(256) void scatter_csr_kernel(
    const int* __restrict__ ei, int E, int EL,
    int* __restrict__ cursor, int* __restrict__ csr_src)
{
    int e = blockIdx.x * blockDim.x + threadIdx.x;
    if (e >= EL) return;
    int s, d;
    if (e < E) { s = ei[e]; d = ei[E + e]; } else { s = d = e - E; }
    int pos = atomicAdd(&cursor[d], 1);
    csr_src[pos] = s;
}

__global__ __launch_bounds__(256) void gemm1_mfma_kernel(
    const unsigned short* __restrict__ xb, const unsigned short* __restrict__ W1T,
    unsigned short* __restrict__ xl1b,
    const float* __restrict__ att_src, const float* __restrict__ att_dst,
    float* __restrict__ a_src, float* __restrict__ a_dst, int M)
{
    __shared__ unsigned short As[128 * 40];
    __shared__ unsigned short Bs[128 * 40];
    const int tid  = threadIdx.x;
    const int row0 = blockIdx.y * 128;
    const int col0 = blockIdx.x * 128;
    const int wave = tid >> 6;
    const int wrow = wave >> 1;
    const int wcol = wave & 1;
    const int lane = tid & 63;
    const int quad = lane >> 4;
    const int l15  = lane & 15;
    const int sm = tid >> 1;
    const int sk = (tid & 1) * 16;

    f32x4 acc[4][4] = {};

    for (int kb = 0; kb < 256; kb += 32) {
        uint4 a0 = make_uint4(0, 0, 0, 0), a1 = make_uint4(0, 0, 0, 0);
        if (row0 + sm < M) {
            const uint4* ap = (const uint4*)(xb + (size_t)(row0 + sm) * 256 + kb + sk);
            a0 = ap[0]; a1 = ap[1];
        }
        uint4* adp = (uint4*)&As[sm * 40 + sk];
        adp[0] = a0; adp[1] = a1;
        const uint4* bp = (const uint4*)(W1T + (size_t)(col0 + sm) * 256 + kb + sk);
        uint4* bd = (uint4*)&Bs[sm * 40 + sk];
        bd[0] = bp[0]; bd[1] = bp[1];
        __syncthreads();
        bf16x8 af[4], bf[4];
        #pragma unroll
        for (int mf = 0; mf < 4; ++mf)
            af[mf] = *(const bf16x8*)&As[(wrow * 64 + mf * 16 + l15) * 40 + quad * 8];
        #pragma unroll
        for (int nf = 0; nf < 4; ++nf)
            bf[nf] = *(const bf16x8*)&Bs[(wcol * 64 + nf * 16 + l15) * 40 + quad * 8];
        #pragma unroll
        for (int mf = 0; mf < 4; ++mf)
            #pragma unroll
            for (int nf = 0; nf < 4; ++nf)
                acc[mf][nf] = __builtin_amdgcn_mfma_f32_16x16x32_bf16(
                    af[mf], bf[nf], acc[mf][nf], 0, 0, 0);
        __syncthreads();
    }

    const int h = blockIdx.x * 2 + wcol;
    float asv[4], adv[4];
    #pragma unroll
    for (int nf = 0; nf < 4; ++nf) {
        asv[nf] = att_src[h * 64 + nf * 16 + l15];
        adv[nf] = att_dst[h * 64 + nf * 16 + l15];
    }
    #pragma unroll
    for (int mf = 0; mf < 4; ++mf) {
        #pragma unroll
        for (int r = 0; r < 4; ++r) {
            const int row = row0 + wrow * 64 + mf * 16 + quad * 4 + r;
            float sv = 0.f, tv = 0.f;
            #pragma unroll
            for (int nf = 0; nf < 4; ++nf) {
                float v = acc[mf][nf][r];
                sv += v * asv[nf];
                tv += v * adv[nf];
            }
            sv += __shfl_xor(sv, 1); tv += __shfl_xor(tv, 1);
            sv += __shfl_xor(sv, 2); tv += __shfl_xor(tv, 2);
            sv += __shfl_xor(sv, 4); tv += __shfl_xor(tv, 4);
            sv += __shfl_xor(sv, 8); tv += __shfl_xor(tv, 8);
            if (row < M) {
                #pragma unroll
                for (int nf = 0; nf < 4; ++nf)
                    xl1b[(size_t)row * 512 + col0 + wcol * 64 + nf * 16 + l15] =
                        f2b(acc[mf][nf][r]);
                if (l15 == 0) { a_src[row * 8 + h] = sv; a_dst[row * 8 + h] = tv; }
            }
        }
    }
}

// ================= shared back end =================
__global__ __launch_bounds__(256) void gather1_kernel(
    const int* __restrict__ rowptr, const int* __restrict__ csr_src,
    const unsigned short* __restrict__ xl1b, const float* __restrict__ a_src,
    const float* __restrict__ a_dst, const float* __restrict__ b1,
    unsigned short* __restrict__ h1, int M)
{
    int wid  = (blockIdx.x * blockDim.x + threadIdx.x) >> 6;
    int lane = threadIdx.x & 63;
    if (wid >= M) return;
    const int start = rowptr[wid], end = rowptr[wid + 1];
    const int h  = lane & 7;
    const int h0 = lane >> 3;
    const float adh = a_dst[wid * 8 + h];
    float dsum = 0.f;
    float acc0 = 0.f, acc1 = 0.f, acc2 = 0.f, acc3 = 0.f;
    float acc4 = 0.f, acc5 = 0.f, acc6 = 0.f, acc7 = 0.f;
    int   sN = csr_src[start];
    float aN = a_src[sN * 8 + h];
    uint4 vN = *(const uint4*)(xl1b + (size_t)sN * 512 + lane * 8);
    for (int j = start; j < end; ++j) {
        const float a = aN;
        const uint4 v = vN;
        const int jn = j + 1;
        if (jn < end) {
            int s2 = csr_src[jn];
            aN = a_src[s2 * 8 + h];
            vN = *(const uint4*)(xl1b + (size_t)s2 * 512 + lane * 8);
        }
        float p = __expf(lrelu(a + adh));
        dsum += p;
        float al = __shfl(p, h0);
        acc0 += blo(v.x) * al; acc1 += bhi(v.x) * al;
        acc2 += blo(v.y) * al; acc3 += bhi(v.y) * al;
        acc4 += blo(v.z) * al; acc5 += bhi(v.z) * al;
        acc6 += blo(v.w) * al; acc7 += bhi(v.w) * al;
    }
    const float ds  = __shfl(dsum, h0);
    const float inv = 1.f / (ds + 1e-16f);
    const float4 ba = *(const float4*)(b1 + lane * 8);
    const float4 bb = *(const float4*)(b1 + lane * 8 + 4);
    uint4 pk;
    pk.x = (unsigned)f2b(fmaxf(acc0 * inv + ba.x, 0.f)) | ((unsigned)f2b(fmaxf(acc1 * inv + ba.y, 0.f)) << 16);
    pk.y = (unsigned)f2b(fmaxf(acc2 * inv + ba.z, 0.f)) | ((unsigned)f2b(fmaxf(acc3 * inv + ba.w, 0.f)) << 16);
    pk.z = (unsigned)f2b(fmaxf(acc4 * inv + bb.x, 0.f)) | ((unsigned)f2b(fmaxf(acc5 * inv + bb.y, 0.f)) << 16);
    pk.w = (unsigned)f2b(fmaxf(acc6 * inv + bb.z, 0.f)) | ((unsigned)f2b(fmaxf(acc7 * inv + bb.w, 0.f)) << 16);
    ((uint4*)(h1 + (size_t)wid * 512))[lane] = pk;
}

__global__ __launch_bounds__(256) void gemm2_mfma_kernel(
    const unsigned short* __restrict__ h1, const unsigned short* __restrict__ W2T,
    const float* __restrict__ att_src2, const float* __restrict__ att_dst2,
    float* __restrict__ xl2, float* __restrict__ a_src2, float* __restrict__ a_dst2,
    int M)
{
    __shared__ unsigned short As[128 * 72];
    __shared__ unsigned short Bs[32 * 72];
    const int tid  = threadIdx.x;
    const int row0 = blockIdx.x * 128;
    const int wv   = tid >> 6;
    const int lane = tid & 63;
    const int quad = lane >> 4;
    const int l15  = lane & 15;

    f32x4 acc[2][2] = {};

    for (int kb = 0; kb < 512; kb += 64) {
        #pragma unroll
        for (int i = 0; i < 4; ++i) {
            int u = tid + 256 * i;
            int r = u >> 3;
            int kq = (u & 7) * 8;
            uint4 v = make_uint4(0, 0, 0, 0);
            if (row0 + r < M)
                v = *(const uint4*)(h1 + (size_t)(row0 + r) * 512 + kb + kq);
            *(uint4*)&As[r * 72 + kq] = v;
        }
        {
            int r = tid >> 3;
            int kq = (tid & 7) * 8;
            *(uint4*)&Bs[r * 72 + kq] = *(const uint4*)(W2T + (size_t)r * 512 + kb + kq);
        }
        __syncthreads();

        #pragma unroll
        for (int ks = 0; ks < 2; ++ks) {
            bf16x8 af[2], bf[2];
            #pragma unroll
            for (int mf = 0; mf < 2; ++mf)
                af[mf] = *(const bf16x8*)&As[(wv * 32 + mf * 16 + l15) * 72 + ks * 32 + quad * 8];
            #pragma unroll
            for (int nf = 0; nf < 2; ++nf)
                bf[nf] = *(const bf16x8*)&Bs[(nf * 16 + l15) * 72 + ks * 32 + quad * 8];
            #pragma unroll
            for (int mf = 0; mf < 2; ++mf)
                #pragma unroll
                for (int nf = 0; nf < 2; ++nf)
                    acc[mf][nf] = __builtin_amdgcn_mfma_f32_16x16x32_bf16(
                        af[mf], bf[nf], acc[mf][nf], 0, 0, 0);
        }
        __syncthreads();
    }

    float as2v[2], ad2v[2];
    #pragma unroll
    for (int nf = 0; nf < 2; ++nf) {
        as2v[nf] = att_src2[nf * 16 + l15];
        ad2v[nf] = att_dst2[nf * 16 + l15];
    }
    #pragma unroll
    for (int mf = 0; mf < 2; ++mf) {
        #pragma unroll
        for (int r = 0; r < 4; ++r) {
            const int row = row0 + wv * 32 + mf * 16 + quad * 4 + r;
            float v0 = acc[mf][0][r], v1 = acc[mf][1][r];
            float sv = v0 * as2v[0] + v1 * as2v[1];
            float tv = v0 * ad2v[0] + v1 * ad2v[1];
            sv += __shfl_xor(sv, 1); tv += __shfl_xor(tv, 1);
            sv += __shfl_xor(sv, 2); tv += __shfl_xor(tv, 2);
            sv += __shfl_xor(sv, 4); tv += __shfl_xor(tv, 4);
            sv += __shfl_xor(sv, 8); tv += __shfl_xor(tv, 8);
            if (row < M) {
                xl2[(size_t)row * 32 + l15]      = v0;
                xl2[(size_t)row * 32 + 16 + l15] = v1;
                if (l15 == 0) { a_src2[row] = sv; a_dst2[row] = tv; }
            }
        }
    }
}

__global__ __launch_bounds__(256) void gather2_head_kernel(
    const int* __restrict__ rowptr, const int* __restrict__ csr_src,
    const float* __restrict__ xl2, const float* __restrict__ a_src2,
    const float* __restrict__ a_dst2, const float* __restrict__ b2,
    const float* __restrict__ fcW, const float* __restrict__ fcb,
    float* __restrict__ emb, float* __restrict__ logits, int M)
{
    __shared__ float sw[32][40];
    for (int i = threadIdx.x; i < 32 * 40; i += 256) sw[i / 40][i % 40] = fcW[i];
    __syncthreads();
    int wid  = (blockIdx.x * blockDim.x + threadIdx.x) >> 6;
    int lane = threadIdx.x & 63;
    if (wid >= M) return;
    const int start = rowptr[wid], end = rowptr[wid + 1];
    const float ad = a_dst2[wid];
    const int sub = lane >> 5;
    const int c   = lane & 31;
    float dsum = 0.f, acc = 0.f;
    int j = start + sub;
    float aN = 0.f, vN = 0.f;
    if (j < end) {
        int s = csr_src[j];
        aN = a_src2[s];
        vN = xl2[(size_t)s * 32 + c];
    }
    for (; j < end; j += 2) {
        const float a = aN, v = vN;
        const int jn = j + 2;
        if (jn < end) {
            int s2 = csr_src[jn];
            aN = a_src2[s2];
            vN = xl2[(size_t)s2 * 32 + c];
        }
        float p = __expf(lrelu(a + ad));
        dsum += p;
        acc += p * v;
    }
    dsum += __shfl_xor(dsum, 32);
    acc  += __shfl_xor(acc, 32);
    const float inv = 1.f / (dsum + 1e-16f);
    float embv = fmaxf(acc * inv + b2[c], 0.f);
    if (sub == 0) emb[(size_t)wid * 32 + c] = embv;
    const int col = (lane < 40) ? lane : 0;
    float lsum = (lane < 40) ? fcb[col] : 0.f;
    #pragma unroll
    for (int k = 0; k < 32; ++k) {
        float ev = __shfl(embv, k);
        lsum += ev * sw[k][col];
    }
    if (lane < 40) logits[(size_t)wid * 40 + lane] = lsum;
}

// ---------- launch ----------
extern "C" void kernel_launch(void* const* d_in, const int* in_sizes, int n_in,
                              void* d_out, int out_size, void* d_ws, size_t ws_size,
                              hipStream_t stream)
{
    const float* x   = (const float*)d_in[0];
    const int*   ei  = (const int*)d_in[1];
    const float* W1  = (const float*)d_in[2];
    const float* as1 = (const float*)d_in[3];
    const float* ad1 = (const float*)d_in[4];
    const float* b1  = (const float*)d_in[5];
    const float* W2  = (const float*)d_in[6];
    const float* as2 = (const float*)d_in[7];
    const float* ad2 = (const float*)d_in[8];
    const float* b2  = (const float*)d_in[9];
    const float* fcW = (const float*)d_in[10];
    const float* fcb = (const float*)d_in[11];

    const int n  = in_sizes[0] / 256;   // 50000
    const int e  = in_sizes[1] / 2;     // 800000
    const int el = e + n;               // with self-loops

    char* ws = (char*)d_ws;
    size_t off = 0;
    unsigned short* xb   = (unsigned short*)(ws + off); off += (size_t)n * 256 * 2;
    unsigned short* w1t  = (unsigned short*)(ws + off); off += (size_t)512 * 256 * 2;
    unsigned short* w2t  = (unsigned short*)(ws + off); off += (size_t)32 * 512 * 2;
    unsigned short* xl1b = (unsigned short*)(ws + off); off += (size_t)n * 512 * 2;
    unsigned short* h1   = (unsigned short*)(ws + off); off += (size_t)n * 512 * 2;
    float* a_src1 = (float*)(ws + off); off += (size_t)n * 8 * 4;
    float* a_dst1 = (float*)(ws + off); off += (size_t)n * 8 * 4;
    float* xl2    = (float*)(ws + off); off += (size_t)n * 32 * 4;
    float* a_src2 = (float*)(ws + off); off += (size_t)n * 4;
    float* a_dst2 = (float*)(ws + off); off += (size_t)n * 4;
    int*   deg    = (int*)(ws + off);   off += (size_t)n * 4;
    int*   rowptr = (int*)(ws + off);   off += (size_t)(n + 1) * 4;
    int*   cursor = (int*)(ws + off);   off += (size_t)n * 4;
    int*   csr_src= (int*)(ws + off);   off += (size_t)el * 4;
    int*   bsum   = (int*)(ws + off);   off += 256 * 4;
    int*   bsoff  = (int*)(ws + off);   off += 256 * 4;

    float* emb    = (float*)d_out;
    float* logits = (float*)d_out + (size_t)n * 32;

    long total8 = (long)n * 256 / 8;
    int  n_tiles_y = (n + 127) / 128;
    int  Mv = n, Ev = e, ELv = el;

    // deg zeroing needed by fallback path (coop path re-zeros in P0; harmless)
    hipMemsetAsync(deg, 0, (size_t)n * 4, stream);

    // ---- try cooperative front end with occupancy-derived grid + checked errors ----
    bool coop_ok = false;
    {
        int maxBlk = 0;
        hipError_t oe = hipOccupancyMaxActiveBlocksPerMultiprocessor(
            &maxBlk, (const void*)fused_front_kernel, 256, 0);
        int numCU = 0;
        hipDeviceProp_t prop;
        int dev = 0;
        if (hipGetDevice(&dev) == hipSuccess &&
            hipGetDeviceProperties(&prop, dev) == hipSuccess)
            numCU = prop.multiProcessorCount;
        if (oe == hipSuccess && maxBlk > 0 && numCU > 0) {
            int gridSz = maxBlk * numCU;
            if (gridSz > 512) gridSz = 512;
            const float* xA = x; unsigned short* xbA = xb;
            const float* W1A = W1; unsigned short* w1tA = w1t;
            const float* W2A = W2; unsigned short* w2tA = w2t;
            const int* eiA = ei;
            const float* as1A = as1; const float* ad1A = ad1;
            void* args[] = {
                (void*)&xA, (void*)&xbA, (void*)&total8,
                (void*)&W1A, (void*)&w1tA, (void*)&W2A, (void*)&w2tA,
                (void*)&eiA, (void*)&Ev, (void*)&ELv,
                (void*)&deg, (void*)&bsum, (void*)&bsoff,
                (void*)&rowptr, (void*)&cursor, (void*)&csr_src,
                (void*)&as1A, (void*)&ad1A,
                (void*)&xl1b, (void*)&a_src1, (void*)&a_dst1,
                (void*)&Mv, (void*)&n_tiles_y
            };
            hipError_t le = hipLaunchCooperativeKernel(
                (const void*)fused_front_kernel, dim3(gridSz), dim3(256), args, 0, stream);
            coop_ok = (le == hipSuccess);
        }
    }

    if (!coop_ok) {
        // ---- fallback: proven R6 multi-kernel front end ----
        const int b_cx = (int)((total8 + 255) / 256);
        const int b_cw = (512 * 256 + 32 * 512 + 255) / 256;
        const int b_dg = (el + 255) / 256;
        prep_kernel<<<b_cx + b_cw + b_dg, 256, 0, stream>>>(
            x, xb, total8, W1, w1t, W2, w2t, ei, e, el, deg, b_cx, b_cw);
        const int nb = (n + 255) / 256;
        scan1_kernel<<<nb, 256, 0, stream>>>(deg, bsum, n);
        scan2_kernel<<<1, 256, 0, stream>>>(bsum, bsoff, nb);
        scan3_kernel<<<nb, 256, 0, stream>>>(deg, bsoff, rowptr, cursor, n, el);
        scatter_csr_kernel<<<(el + 255) / 256, 256, 0, stream>>>(ei, e, el, cursor, csr_src);
        gemm1_mfma_kernel<<<dim3(4, (n + 127) / 128), 256, 0, stream>>>(
            xb, w1t, xl1b, as1, ad1, a_src1, a_dst1, n);
    }

    gather1_kernel<<<((size_t)n * 64 + 255) / 256, 256, 0, stream>>>(
        rowptr, csr_src, xl1b, a_src1, a_dst1, b1, h1, n);
    gemm2_mfma_kernel<<<(n + 127) / 128, 256, 0, stream>>>(
        h1, w2t, as2, ad2, xl2, a_src2, a_dst2, n);
    gather2_head_kernel<<<((size_t)n * 64 + 255) / 256, 256, 0, stream>>>(
        rowptr, csr_src, xl2, a_src2, a_dst2, b2, fcW, fcb, emb, logits, n);
}

// Round 10
// 456.961 us; speedup vs baseline: 1.4101x; 1.4101x over previous
//
#include <hip/hip_runtime.h>
#include <hip/hip_bf16.h>
#include <math.h>

#define NEG_SLOPE 0.2f

typedef __attribute__((ext_vector_type(8))) short bf16x8;
typedef __attribute__((ext_vector_type(4))) float f32x4;

__device__ __forceinline__ float lrelu(float x) { return x > 0.f ? x : NEG_SLOPE * x; }
__device__ __forceinline__ float blo(unsigned u) { return __uint_as_float(u << 16); }
__device__ __forceinline__ float bhi(unsigned u) { return __uint_as_float(u & 0xffff0000u); }
__device__ __forceinline__ unsigned short f2b(float f) {
    __hip_bfloat16 b = __float2bfloat16(f);
    return *(unsigned short*)&b;
}

// ---------- prep: convert x->bf16, W1->W1T bf16, W2->W2T bf16, deg histogram ----------
__global__ __launch_bounds__(256) void prep_kernel(
    const float* __restrict__ x, unsigned short* __restrict__ xb, long total8,
    const float* __restrict__ W1, unsigned short* __restrict__ W1T,
    const float* __restrict__ W2, unsigned short* __restrict__ W2T,
    const int* __restrict__ ei, int E, int EL, int* __restrict__ deg,
    int b_cx, int b_cw)
{
    const int b = blockIdx.x;
    if (b < b_cx) {
        long i = (long)b * 256 + threadIdx.x;
        if (i >= total8) return;
        const float4* src = (const float4*)x + 2 * i;
        float4 a = src[0], v = src[1];
        uint4 pk;
        pk.x = (unsigned)f2b(a.x) | ((unsigned)f2b(a.y) << 16);
        pk.y = (unsigned)f2b(a.z) | ((unsigned)f2b(a.w) << 16);
        pk.z = (unsigned)f2b(v.x) | ((unsigned)f2b(v.y) << 16);
        pk.w = (unsigned)f2b(v.z) | ((unsigned)f2b(v.w) << 16);
        ((uint4*)xb)[i] = pk;
    } else if (b < b_cx + b_cw) {
        int i = (b - b_cx) * 256 + threadIdx.x;
        if (i < 512 * 256) {
            int nn = i >> 8, k = i & 255;
            W1T[nn * 256 + k] = f2b(W1[k * 512 + nn]);
        } else if (i < 512 * 256 + 32 * 512) {
            int j = i - 512 * 256;
            int c = j >> 9, k = j & 511;
            W2T[c * 512 + k] = f2b(W2[k * 32 + c]);
        }
    } else {
        int e = (b - b_cx - b_cw) * 256 + threadIdx.x;
        if (e >= EL) return;
        int d = (e < E) ? ei[E + e] : e - E;
        atomicAdd(&deg[d], 1);
    }
}

// ---------- two-level scan ----------
__global__ __launch_bounds__(256) void scan1_kernel(
    const int* __restrict__ deg, int* __restrict__ bsum, int n)
{
    __shared__ int red[256];
    int t = threadIdx.x, i = blockIdx.x * 256 + t;
    red[t] = (i < n) ? deg[i] : 0;
    __syncthreads();
    for (int off = 128; off > 0; off >>= 1) {
        if (t < off) red[t] += red[t + off];
        __syncthreads();
    }
    if (t == 0) bsum[blockIdx.x] = red[0];
}

__global__ __launch_bounds__(256) void scan2_kernel(
    const int* __restrict__ bsum, int* __restrict__ bsoff, int B)
{
    __shared__ int part[256];
    int t = threadIdx.x;
    int v = (t < B) ? bsum[t] : 0;
    part[t] = v;
    __syncthreads();
    for (int off = 1; off < 256; off <<= 1) {
        int tmp = (t >= off) ? part[t - off] : 0;
        __syncthreads();
        part[t] += tmp;
        __syncthreads();
    }
    if (t < B) bsoff[t] = part[t] - v;
}

__global__ __launch_bounds__(256) void scan3_kernel(
    const int* __restrict__ deg, const int* __restrict__ bsoff,
    int* __restrict__ rowptr, int* __restrict__ cursor, int n, int EL)
{
    __shared__ int part[256];
    int t = threadIdx.x, b = blockIdx.x, i = b * 256 + t;
    int v = (i < n) ? deg[i] : 0;
    part[t] = v;
    __syncthreads();
    for (int off = 1; off < 256; off <<= 1) {
        int tmp = (t >= off) ? part[t - off] : 0;
        __syncthreads();
        part[t] += tmp;
        __syncthreads();
    }
    if (i < n) {
        int r = bsoff[b] + part[t] - v;
        rowptr[i] = r;
        cursor[i] = r;
    }
    if (i == n - 1) rowptr[n] = EL;
}

// ---------- merged CSR-scatter + GEMM1 (independent work, one dispatch) ----------
// blocks [0, b_sc): scatter edges to csr_src.  blocks [b_sc, b_sc+4*n_tiles_y): GEMM1 tiles.
// GEMM1: 128x128 tile, BK=32, LDS rows padded 32->40, fused att1 dots (R4-proven config).
__global__ __launch_bounds__(256) void scatter_gemm1_kernel(
    const int* __restrict__ ei, int E, int EL,
    int* __restrict__ cursor, int* __restrict__ csr_src,
    const unsigned short* __restrict__ xb, const unsigned short* __restrict__ W1T,
    unsigned short* __restrict__ xl1b,
    const float* __restrict__ att_src, const float* __restrict__ att_dst,
    float* __restrict__ a_src, float* __restrict__ a_dst,
    int M, int b_sc)
{
    if (blockIdx.x < b_sc) {
        int e = blockIdx.x * 256 + threadIdx.x;
        if (e >= EL) return;
        int s, d;
        if (e < E) { s = ei[e]; d = ei[E + e]; } else { s = d = e - E; }
        int pos = atomicAdd(&cursor[d], 1);
        csr_src[pos] = s;
        return;
    }
    __shared__ unsigned short As[128 * 40];
    __shared__ unsigned short Bs[128 * 40];
    const int t    = blockIdx.x - b_sc;
    const int row0 = (t >> 2) * 128;
    const int col0 = (t & 3) * 128;
    const int tid  = threadIdx.x;
    const int wave = tid >> 6;
    const int wrow = wave >> 1;
    const int wcol = wave & 1;
    const int lane = tid & 63;
    const int quad = lane >> 4;
    const int l15  = lane & 15;
    const int sm = tid >> 1;
    const int sk = (tid & 1) * 16;

    f32x4 acc[4][4] = {};

    for (int kb = 0; kb < 256; kb += 32) {
        uint4 a0 = make_uint4(0, 0, 0, 0), a1 = make_uint4(0, 0, 0, 0);
        if (row0 + sm < M) {
            const uint4* ap = (const uint4*)(xb + (size_t)(row0 + sm) * 256 + kb + sk);
            a0 = ap[0]; a1 = ap[1];
        }
        uint4* adp = (uint4*)&As[sm * 40 + sk];
        adp[0] = a0; adp[1] = a1;
        const uint4* bp = (const uint4*)(W1T + (size_t)(col0 + sm) * 256 + kb + sk);
        uint4* bd = (uint4*)&Bs[sm * 40 + sk];
        bd[0] = bp[0]; bd[1] = bp[1];
        __syncthreads();
        bf16x8 af[4], bf[4];
        #pragma unroll
        for (int mf = 0; mf < 4; ++mf)
            af[mf] = *(const bf16x8*)&As[(wrow * 64 + mf * 16 + l15) * 40 + quad * 8];
        #pragma unroll
        for (int nf = 0; nf < 4; ++nf)
            bf[nf] = *(const bf16x8*)&Bs[(wcol * 64 + nf * 16 + l15) * 40 + quad * 8];
        #pragma unroll
        for (int mf = 0; mf < 4; ++mf)
            #pragma unroll
            for (int nf = 0; nf < 4; ++nf)
                acc[mf][nf] = __builtin_amdgcn_mfma_f32_16x16x32_bf16(
                    af[mf], bf[nf], acc[mf][nf], 0, 0, 0);
        __syncthreads();
    }

    const int h = (t & 3) * 2 + wcol;
    float asv[4], adv[4];
    #pragma unroll
    for (int nf = 0; nf < 4; ++nf) {
        asv[nf] = att_src[h * 64 + nf * 16 + l15];
        adv[nf] = att_dst[h * 64 + nf * 16 + l15];
    }
    #pragma unroll
    for (int mf = 0; mf < 4; ++mf) {
        #pragma unroll
        for (int r = 0; r < 4; ++r) {
            const int row = row0 + wrow * 64 + mf * 16 + quad * 4 + r;
            float sv = 0.f, tv = 0.f;
            #pragma unroll
            for (int nf = 0; nf < 4; ++nf) {
                float v = acc[mf][nf][r];
                sv += v * asv[nf];
                tv += v * adv[nf];
            }
            sv += __shfl_xor(sv, 1); tv += __shfl_xor(tv, 1);
            sv += __shfl_xor(sv, 2); tv += __shfl_xor(tv, 2);
            sv += __shfl_xor(sv, 4); tv += __shfl_xor(tv, 4);
            sv += __shfl_xor(sv, 8); tv += __shfl_xor(tv, 8);
            if (row < M) {
                #pragma unroll
                for (int nf = 0; nf < 4; ++nf)
                    xl1b[(size_t)row * 512 + col0 + wcol * 64 + nf * 16 + l15] =
                        f2b(acc[mf][nf][r]);
                if (l15 == 0) { a_src[row * 8 + h] = sv; a_dst[row * 8 + h] = tv; }
            }
        }
    }
}

// ---------- fused layer-1 softmax + aggregate + bias + relu -> h1 (bf16) ----------
__global__ __launch_bounds__(256) void gather1_kernel(
    const int* __restrict__ rowptr, const int* __restrict__ csr_src,
    const unsigned short* __restrict__ xl1b, const float* __restrict__ a_src,
    const float* __restrict__ a_dst, const float* __restrict__ b1,
    unsigned short* __restrict__ h1, int M)
{
    int wid  = (blockIdx.x * blockDim.x + threadIdx.x) >> 6;
    int lane = threadIdx.x & 63;
    if (wid >= M) return;
    const int start = rowptr[wid], end = rowptr[wid + 1];
    const int h  = lane & 7;
    const int h0 = lane >> 3;
    const float adh = a_dst[wid * 8 + h];
    float dsum = 0.f;
    float acc0 = 0.f, acc1 = 0.f, acc2 = 0.f, acc3 = 0.f;
    float acc4 = 0.f, acc5 = 0.f, acc6 = 0.f, acc7 = 0.f;
    int   sN = csr_src[start];
    float aN = a_src[sN * 8 + h];
    uint4 vN = *(const uint4*)(xl1b + (size_t)sN * 512 + lane * 8);
    for (int j = start; j < end; ++j) {
        const float a = aN;
        const uint4 v = vN;
        const int jn = j + 1;
        if (jn < end) {
            int s2 = csr_src[jn];
            aN = a_src[s2 * 8 + h];
            vN = *(const uint4*)(xl1b + (size_t)s2 * 512 + lane * 8);
        }
        float p = __expf(lrelu(a + adh));
        dsum += p;
        float al = __shfl(p, h0);
        acc0 += blo(v.x) * al; acc1 += bhi(v.x) * al;
        acc2 += blo(v.y) * al; acc3 += bhi(v.y) * al;
        acc4 += blo(v.z) * al; acc5 += bhi(v.z) * al;
        acc6 += blo(v.w) * al; acc7 += bhi(v.w) * al;
    }
    const float ds  = __shfl(dsum, h0);
    const float inv = 1.f / (ds + 1e-16f);
    const float4 ba = *(const float4*)(b1 + lane * 8);
    const float4 bb = *(const float4*)(b1 + lane * 8 + 4);
    uint4 pk;
    pk.x = (unsigned)f2b(fmaxf(acc0 * inv + ba.x, 0.f)) | ((unsigned)f2b(fmaxf(acc1 * inv + ba.y, 0.f)) << 16);
    pk.y = (unsigned)f2b(fmaxf(acc2 * inv + ba.z, 0.f)) | ((unsigned)f2b(fmaxf(acc3 * inv + ba.w, 0.f)) << 16);
    pk.z = (unsigned)f2b(fmaxf(acc4 * inv + bb.x, 0.f)) | ((unsigned)f2b(fmaxf(acc5 * inv + bb.y, 0.f)) << 16);
    pk.w = (unsigned)f2b(fmaxf(acc6 * inv + bb.z, 0.f)) | ((unsigned)f2b(fmaxf(acc7 * inv + bb.w, 0.f)) << 16);
    ((uint4*)(h1 + (size_t)wid * 512))[lane] = pk;
}

// ---------- GEMM2 (MFMA bf16): xl2[M,32] = h1[M,512] @ W2; fused att2 dots ----------
__global__ __launch_bounds__(256) void gemm2_mfma_kernel(
    const unsigned short* __restrict__ h1, const unsigned short* __restrict__ W2T,
    const float* __restrict__ att_src2, const float* __restrict__ att_dst2,
    float* __restrict__ xl2, float* __restrict__ a_src2, float* __restrict__ a_dst2,
    int M)
{
    __shared__ unsigned short As[128 * 72];
    __shared__ unsigned short Bs[32 * 72];
    const int tid  = threadIdx.x;
    const int row0 = blockIdx.x * 128;
    const int wv   = tid >> 6;
    const int lane = tid & 63;
    const int quad = lane >> 4;
    const int l15  = lane & 15;

    f32x4 acc[2][2] = {};

    for (int kb = 0; kb < 512; kb += 64) {
        #pragma unroll
        for (int i = 0; i < 4; ++i) {
            int u = tid + 256 * i;
            int r = u >> 3;
            int kq = (u & 7) * 8;
            uint4 v = make_uint4(0, 0, 0, 0);
            if (row0 + r < M)
                v = *(const uint4*)(h1 + (size_t)(row0 + r) * 512 + kb + kq);
            *(uint4*)&As[r * 72 + kq] = v;
        }
        {
            int r = tid >> 3;
            int kq = (tid & 7) * 8;
            *(uint4*)&Bs[r * 72 + kq] = *(const uint4*)(W2T + (size_t)r * 512 + kb + kq);
        }
        __syncthreads();

        #pragma unroll
        for (int ks = 0; ks < 2; ++ks) {
            bf16x8 af[2], bf[2];
            #pragma unroll
            for (int mf = 0; mf < 2; ++mf)
                af[mf] = *(const bf16x8*)&As[(wv * 32 + mf * 16 + l15) * 72 + ks * 32 + quad * 8];
            #pragma unroll
            for (int nf = 0; nf < 2; ++nf)
                bf[nf] = *(const bf16x8*)&Bs[(nf * 16 + l15) * 72 + ks * 32 + quad * 8];
            #pragma unroll
            for (int mf = 0; mf < 2; ++mf)
                #pragma unroll
                for (int nf = 0; nf < 2; ++nf)
                    acc[mf][nf] = __builtin_amdgcn_mfma_f32_16x16x32_bf16(
                        af[mf], bf[nf], acc[mf][nf], 0, 0, 0);
        }
        __syncthreads();
    }

    float as2v[2], ad2v[2];
    #pragma unroll
    for (int nf = 0; nf < 2; ++nf) {
        as2v[nf] = att_src2[nf * 16 + l15];
        ad2v[nf] = att_dst2[nf * 16 + l15];
    }
    #pragma unroll
    for (int mf = 0; mf < 2; ++mf) {
        #pragma unroll
        for (int r = 0; r < 4; ++r) {
            const int row = row0 + wv * 32 + mf * 16 + quad * 4 + r;
            float v0 = acc[mf][0][r], v1 = acc[mf][1][r];
            float sv = v0 * as2v[0] + v1 * as2v[1];
            float tv = v0 * ad2v[0] + v1 * ad2v[1];
            sv += __shfl_xor(sv, 1); tv += __shfl_xor(tv, 1);
            sv += __shfl_xor(sv, 2); tv += __shfl_xor(tv, 2);
            sv += __shfl_xor(sv, 4); tv += __shfl_xor(tv, 4);
            sv += __shfl_xor(sv, 8); tv += __shfl_xor(tv, 8);
            if (row < M) {
                xl2[(size_t)row * 32 + l15]      = v0;
                xl2[(size_t)row * 32 + 16 + l15] = v1;
                if (l15 == 0) { a_src2[row] = sv; a_dst2[row] = tv; }
            }
        }
    }
}

// ---------- fused layer-2 softmax + aggregate + bias + relu + fc head ----------
// 4 edges in flight: lane = 16*g + c2; group g handles edges start+g (step 4),
// lane covers channels (2*c2, 2*c2+1) as float2. Cross-group reduce via xor 16/32.
__global__ __launch_bounds__(256) void gather2_head_kernel(
    const int* __restrict__ rowptr, const int* __restrict__ csr_src,
    const float* __restrict__ xl2, const float* __restrict__ a_src2,
    const float* __restrict__ a_dst2, const float* __restrict__ b2,
    const float* __restrict__ fcW, const float* __restrict__ fcb,
    float* __restrict__ emb, float* __restrict__ logits, int M)
{
    __shared__ float sw[32][40];
    for (int i = threadIdx.x; i < 32 * 40; i += 256) sw[i / 40][i % 40] = fcW[i];
    __syncthreads();
    int wid  = (blockIdx.x * blockDim.x + threadIdx.x) >> 6;
    int lane = threadIdx.x & 63;
    if (wid >= M) return;
    const int start = rowptr[wid], end = rowptr[wid + 1];
    const float ad = a_dst2[wid];
    const int g  = lane >> 4;        // 0..3: edge slot
    const int c2 = lane & 15;        // channel pair
    float dsum = 0.f;
    float accx = 0.f, accy = 0.f;
    for (int j = start + g; j < end; j += 4) {
        int s = csr_src[j];
        float p = __expf(lrelu(a_src2[s] + ad));
        dsum += p;
        float2 v = *(const float2*)(xl2 + (size_t)s * 32 + 2 * c2);
        accx += p * v.x;
        accy += p * v.y;
    }
    dsum += __shfl_xor(dsum, 16); accx += __shfl_xor(accx, 16); accy += __shfl_xor(accy, 16);
    dsum += __shfl_xor(dsum, 32); accx += __shfl_xor(accx, 32); accy += __shfl_xor(accy, 32);
    const float inv = 1.f / (dsum + 1e-16f);
    const float2 b2v = *(const float2*)(b2 + 2 * c2);
    float ex = fmaxf(accx * inv + b2v.x, 0.f);
    float ey = fmaxf(accy * inv + b2v.y, 0.f);
    if (g == 0) *(float2*)(emb + (size_t)wid * 32 + 2 * c2) = make_float2(ex, ey);
    // logits: lane < 40 computes column `lane`; emb pairs broadcast from lanes 0..15
    const int col = (lane < 40) ? lane : 0;
    float lsum = (lane < 40) ? fcb[col] : 0.f;
    #pragma unroll
    for (int k = 0; k < 16; ++k) {
        float vx = __shfl(ex, k);
        float vy = __shfl(ey, k);
        lsum += vx * sw[2 * k][col] + vy * sw[2 * k + 1][col];
    }
    if (lane < 40) logits[(size_t)wid * 40 + lane] = lsum;
}

// ---------- launch ----------
extern "C" void kernel_launch(void* const* d_in, const int* in_sizes, int n_in,
                              void* d_out, int out_size, void* d_ws, size_t ws_size,
                              hipStream_t stream)
{
    const float* x   = (const float*)d_in[0];
    const int*   ei  = (const int*)d_in[1];
    const float* W1  = (const float*)d_in[2];
    const float* as1 = (const float*)d_in[3];
    const float* ad1 = (const float*)d_in[4];
    const float* b1  = (const float*)d_in[5];
    const float* W2  = (const float*)d_in[6];
    const float* as2 = (const float*)d_in[7];
    const float* ad2 = (const float*)d_in[8];
    const float* b2  = (const float*)d_in[9];
    const float* fcW = (const float*)d_in[10];
    const float* fcb = (const float*)d_in[11];

    const int n  = in_sizes[0] / 256;   // 50000
    const int e  = in_sizes[1] / 2;     // 800000
    const int el = e + n;               // with self-loops

    char* ws = (char*)d_ws;
    size_t off = 0;
    unsigned short* xb   = (unsigned short*)(ws + off); off += (size_t)n * 256 * 2;
    unsigned short* w1t  = (unsigned short*)(ws + off); off += (size_t)512 * 256 * 2;
    unsigned short* w2t  = (unsigned short*)(ws + off); off += (size_t)32 * 512 * 2;
    unsigned short* xl1b = (unsigned short*)(ws + off); off += (size_t)n * 512 * 2;
    unsigned short* h1   = (unsigned short*)(ws + off); off += (size_t)n * 512 * 2;
    float* a_src1 = (float*)(ws + off); off += (size_t)n * 8 * 4;
    float* a_dst1 = (float*)(ws + off); off += (size_t)n * 8 * 4;
    float* xl2    = (float*)(ws + off); off += (size_t)n * 32 * 4;
    float* a_src2 = (float*)(ws + off); off += (size_t)n * 4;
    float* a_dst2 = (float*)(ws + off); off += (size_t)n * 4;
    int*   deg    = (int*)(ws + off);   off += (size_t)n * 4;
    int*   rowptr = (int*)(ws + off);   off += (size_t)(n + 1) * 4;
    int*   cursor = (int*)(ws + off);   off += (size_t)n * 4;
    int*   csr_src= (int*)(ws + off);   off += (size_t)el * 4;
    int*   bsum   = (int*)(ws + off);   off += 256 * 4;
    int*   bsoff  = (int*)(ws + off);   off += 256 * 4;

    float* emb    = (float*)d_out;
    float* logits = (float*)d_out + (size_t)n * 32;

    hipMemsetAsync(deg, 0, (size_t)n * 4, stream);

    const long total8 = (long)n * 256 / 8;
    const int b_cx = (int)((total8 + 255) / 256);
    const int b_cw = (512 * 256 + 32 * 512 + 255) / 256;
    const int b_dg = (el + 255) / 256;
    prep_kernel<<<b_cx + b_cw + b_dg, 256, 0, stream>>>(
        x, xb, total8, W1, w1t, W2, w2t, ei, e, el, deg, b_cx, b_cw);

    const int nb = (n + 255) / 256;
    scan1_kernel<<<nb, 256, 0, stream>>>(deg, bsum, n);
    scan2_kernel<<<1, 256, 0, stream>>>(bsum, bsoff, nb);
    scan3_kernel<<<nb, 256, 0, stream>>>(deg, bsoff, rowptr, cursor, n, el);

    // merged scatter + GEMM1 (independent work overlapped in one dispatch)
    const int b_sc = (el + 255) / 256;
    const int n_tiles_y = (n + 127) / 128;
    scatter_gemm1_kernel<<<b_sc + 4 * n_tiles_y, 256, 0, stream>>>(
        ei, e, el, cursor, csr_src,
        xb, w1t, xl1b, as1, ad1, a_src1, a_dst1, n, b_sc);

    gather1_kernel<<<((size_t)n * 64 + 255) / 256, 256, 0, stream>>>(
        rowptr, csr_src, xl1b, a_src1, a_dst1, b1, h1, n);
    gemm2_mfma_kernel<<<(n + 127) / 128, 256, 0, stream>>>(
        h1, w2t, as2, ad2, xl2, a_src2, a_dst2, n);
    gather2_head_kernel<<<((size_t)n * 64 + 255) / 256, 256, 0, stream>>>(
        rowptr, csr_src, xl2, a_src2, a_dst2, b2, fcW, fcb, emb, logits, n);
}